// Round 3
// baseline (1453.473 us; speedup 1.0000x reference)
//
#include <hip/hip_runtime.h>

#define T_TOK 2048
#define H_DIM 2048
#define E_NUM 32
#define I_DIM 768
#define TOPK 8

typedef __attribute__((ext_vector_type(8))) _Float16 f16x8;
typedef __attribute__((ext_vector_type(4))) _Float16 f16x4;
typedef __attribute__((ext_vector_type(4))) float f32x4;

// ---------------- x fp32 -> fp16 ----------------
__global__ __launch_bounds__(256) void cvt_x_kernel(const float* __restrict__ x,
                                                    _Float16* __restrict__ xh) {
    int i = blockIdx.x * 256 + threadIdx.x;  // one f32x4 per thread
    f32x4 f = ((const f32x4*)x)[i];
    f16x4 h;
    h[0] = (_Float16)f[0]; h[1] = (_Float16)f[1];
    h[2] = (_Float16)f[2]; h[3] = (_Float16)f[3];
    ((f16x4*)xh)[i] = h;
}

// ---------------- router: logits (fp32) + top-8 + softmax ----------------
__global__ __launch_bounds__(256) void router_kernel(const float* __restrict__ x,
                                                     const float* __restrict__ gw,
                                                     int* __restrict__ sel_e,
                                                     float* __restrict__ sel_w,
                                                     int* __restrict__ counts) {
    int t = blockIdx.x;
    int tid = threadIdx.x, lane = tid & 63, wave = tid >> 6;
    __shared__ float logits[E_NUM];
    const float* xr = x + (size_t)t * H_DIM;
    float xv[32];
#pragma unroll
    for (int c = 0; c < 32; ++c) xv[c] = xr[lane + c * 64];
    for (int j = 0; j < 8; ++j) {
        int e = wave * 8 + j;
        const float* wr = gw + (size_t)e * H_DIM;
        float acc = 0.f;
#pragma unroll
        for (int c = 0; c < 32; ++c) acc += xv[c] * wr[lane + c * 64];
#pragma unroll
        for (int s = 32; s > 0; s >>= 1) acc += __shfl_xor(acc, s, 64);
        if (lane == 0) logits[e] = acc;
    }
    __syncthreads();
    if (tid == 0) {
        float lg[E_NUM];
        for (int e2 = 0; e2 < E_NUM; ++e2) lg[e2] = logits[e2];
        unsigned taken = 0;
        float sv[TOPK]; int se[TOPK];
        for (int k = 0; k < TOPK; ++k) {          // top-k, ties -> lowest index (matches lax.top_k)
            float best = -3.4e38f; int bi = 0;
            for (int e2 = 0; e2 < E_NUM; ++e2)
                if (!((taken >> e2) & 1u) && lg[e2] > best) { best = lg[e2]; bi = e2; }
            taken |= 1u << bi; sv[k] = best; se[k] = bi;
        }
        float m = sv[0], s = 0.f;
        for (int k = 0; k < TOPK; ++k) { sv[k] = expf(sv[k] - m); s += sv[k]; }
        float inv = 1.f / s;
        for (int k = 0; k < TOPK; ++k) {
            sel_e[t * TOPK + k] = se[k];
            sel_w[t * TOPK + k] = sv[k] * inv;
            atomicAdd(&counts[se[k]], 1);
        }
    }
}

// ---------------- exclusive scan over 32 expert counts ----------------
__global__ void scan_kernel(const int* __restrict__ counts, int* __restrict__ offs) {
    if (threadIdx.x == 0) {
        int s = 0;
        for (int e = 0; e < E_NUM; ++e) { offs[e] = s; s += counts[e]; }
        offs[E_NUM] = s;
    }
}

// ---------------- scatter (token,weight) pairs into per-expert lists ----------------
__global__ __launch_bounds__(256) void scatter_kernel(const int* __restrict__ sel_e,
                                                      const float* __restrict__ sel_w,
                                                      const int* __restrict__ offs,
                                                      int* __restrict__ cursor,
                                                      int* __restrict__ pair_token,
                                                      float* __restrict__ pair_w) {
    int t = blockIdx.x * 256 + threadIdx.x;
    if (t >= T_TOK) return;
    for (int k = 0; k < TOPK; ++k) {
        int e = sel_e[t * TOPK + k];
        int pos = atomicAdd(&cursor[e], 1);
        int slot = offs[e] + pos;
        pair_token[slot] = t;
        pair_w[slot] = sel_w[t * TOPK + k];
    }
}

// ---------------- mlp1: h = silu(x@Wg^T) * (x@Wu^T) * pair_w, fp16 MFMA ----------------
// BM=256 tokens, BN=64 I-cols, fused g+u (acc 128 f32/thread -> hard 2 blocks/CU cap).
// Plain dim3 dispatch: x=mt (stragglers dispatched early, mt-twins of a weight slab
// adjacent in dispatch order -> concurrent chip-wide -> L3 absorbs twin re-fetch),
// hardware round-robin spreads blocks over all XCDs (load balance).
#define M1_MT 8
#define M1_NT 12
__global__ __launch_bounds__(256, 2) void mlp1_kernel(const _Float16* __restrict__ xh,
                                                      const float* __restrict__ wg,
                                                      const float* __restrict__ wu,
                                                      const int* __restrict__ offs,
                                                      const int* __restrict__ pair_token,
                                                      const float* __restrict__ pair_w,
                                                      _Float16* __restrict__ h_buf) {
    int mt = blockIdx.x, nt = blockIdx.y, e = blockIdx.z;
    int base = offs[e], cnt = offs[e + 1] - base;
    if (mt * 256 >= cnt) return;
    int tid = threadIdx.x, lane = tid & 63, wave = tid >> 6;

    __shared__ _Float16 As[256 * 40];   // pad stride 40 halves
    __shared__ _Float16 Bg[64 * 40];
    __shared__ _Float16 Bu[64 * 40];

    // A staging: 256 rows x 32 halves = 1024 chunks of 8 halves; 4 chunks/thread
    const _Float16* aSrc[4]; int aDst[4];
#pragma unroll
    for (int i = 0; i < 4; ++i) {
        int c = tid + i * 256;
        int row = c >> 2, col8 = c & 3;
        int g = mt * 256 + row;
        int tok = (g < cnt) ? pair_token[base + g] : pair_token[base];
        aSrc[i] = xh + (size_t)tok * H_DIM + col8 * 8;
        aDst[i] = row * 40 + col8 * 8;
    }
    // B staging: 64 rows x 32 floats per matrix = 512 f32x4 chunks; 2 chunks/thread
    const float* gSrc[2]; const float* uSrc[2]; int bDst[2];
#pragma unroll
    for (int i = 0; i < 2; ++i) {
        int c = tid + i * 256;
        int row = c >> 3, col4 = c & 7;
        size_t wOff = ((size_t)e * I_DIM + nt * 64 + row) * H_DIM + col4 * 4;
        gSrc[i] = wg + wOff; uSrc[i] = wu + wOff;
        bDst[i] = row * 40 + col4 * 4;
    }

    const f32x4 zero = {0.f, 0.f, 0.f, 0.f};
    f32x4 accg[4][4], accu[4][4];
#pragma unroll
    for (int mi = 0; mi < 4; ++mi)
#pragma unroll
        for (int ni = 0; ni < 4; ++ni) { accg[mi][ni] = zero; accu[mi][ni] = zero; }

    int m16 = lane & 15, quad = lane >> 4;

    // register prefetch (T14): regs hold slab k0; prefetch k0+32 overlaps MFMA
    f16x8 aReg[4]; f32x4 gReg[2], uReg[2];
#pragma unroll
    for (int i = 0; i < 4; ++i) aReg[i] = *(const f16x8*)(aSrc[i]);
#pragma unroll
    for (int i = 0; i < 2; ++i) { gReg[i] = *(const f32x4*)(gSrc[i]); uReg[i] = *(const f32x4*)(uSrc[i]); }

    for (int k0 = 0; k0 < H_DIM; k0 += 32) {
#pragma unroll
        for (int i = 0; i < 4; ++i)
            *(f16x8*)&As[aDst[i]] = aReg[i];
#pragma unroll
        for (int i = 0; i < 2; ++i) {
            f16x4 hg, hu;
#pragma unroll
            for (int q = 0; q < 4; ++q) { hg[q] = (_Float16)gReg[i][q]; hu[q] = (_Float16)uReg[i][q]; }
            *(f16x4*)&Bg[bDst[i]] = hg;
            *(f16x4*)&Bu[bDst[i]] = hu;
        }
        __syncthreads();
        if (k0 + 32 < H_DIM) {
            int kn = k0 + 32;
#pragma unroll
            for (int i = 0; i < 4; ++i) aReg[i] = *(const f16x8*)(aSrc[i] + kn);
#pragma unroll
            for (int i = 0; i < 2; ++i) { gReg[i] = *(const f32x4*)(gSrc[i] + kn); uReg[i] = *(const f32x4*)(uSrc[i] + kn); }
        }
        f16x8 a[4], bg[4], bu[4];
#pragma unroll
        for (int mi = 0; mi < 4; ++mi)
            a[mi] = *(const f16x8*)&As[(wave * 64 + mi * 16 + m16) * 40 + quad * 8];
#pragma unroll
        for (int ni = 0; ni < 4; ++ni) {
            int r = (ni * 16 + m16) * 40 + quad * 8;
            bg[ni] = *(const f16x8*)&Bg[r];
            bu[ni] = *(const f16x8*)&Bu[r];
        }
#pragma unroll
        for (int mi = 0; mi < 4; ++mi)
#pragma unroll
            for (int ni = 0; ni < 4; ++ni) {
                accg[mi][ni] = __builtin_amdgcn_mfma_f32_16x16x32_f16(a[mi], bg[ni], accg[mi][ni], 0, 0, 0);
                accu[mi][ni] = __builtin_amdgcn_mfma_f32_16x16x32_f16(a[mi], bu[ni], accu[mi][ni], 0, 0, 0);
            }
        __syncthreads();
    }

    // epilogue: silu(g)*u*pair_w -> h_buf (fp16). C/D: col=lane&15, row=quad*4+reg
#pragma unroll
    for (int mi = 0; mi < 4; ++mi) {
#pragma unroll
        for (int reg = 0; reg < 4; ++reg) {
            int rloc = wave * 64 + mi * 16 + quad * 4 + reg;
            int g = mt * 256 + rloc;
            if (g >= cnt) continue;
            int slot = base + g;
            float pw = pair_w[slot];
#pragma unroll
            for (int ni = 0; ni < 4; ++ni) {
                int col = nt * 64 + ni * 16 + m16;
                float gv = accg[mi][ni][reg];
                float uv = accu[mi][ni][reg];
                float hv = (gv / (1.f + expf(-gv))) * uv * pw;
                h_buf[(size_t)slot * I_DIM + col] = (_Float16)hv;
            }
        }
    }
}

// ---------------- mlp2: out[t] += h_slot @ Wd^T (scatter-add) ----------------
// BM=256 slots, BN=128 H-cols. Plain dim3 dispatch, x=mt (same rationale as mlp1).
#define M2_MT 8
#define M2_NT 16
__global__ __launch_bounds__(256, 2) void mlp2_kernel(const _Float16* __restrict__ h_buf,
                                                      const float* __restrict__ wd,
                                                      const int* __restrict__ offs,
                                                      const int* __restrict__ pair_token,
                                                      float* __restrict__ out) {
    int mt = blockIdx.x, nt = blockIdx.y, e = blockIdx.z;
    int base = offs[e], cnt = offs[e + 1] - base;
    if (mt * 256 >= cnt) return;
    int tid = threadIdx.x, lane = tid & 63, wave = tid >> 6;

    __shared__ _Float16 As[256 * 40];
    __shared__ _Float16 Bs[128 * 40];

    // A staging: 256 rows x 32 halves -> 4 chunks/thread (slots are contiguous, no gather)
    const _Float16* aSrc[4]; int aDst[4];
#pragma unroll
    for (int i = 0; i < 4; ++i) {
        int c = tid + i * 256;
        int row = c >> 2, col8 = c & 3;
        int g = mt * 256 + row;
        int slot = (g < cnt) ? (base + g) : base;  // clamp: avoid OOB reads past h_buf
        aSrc[i] = h_buf + (size_t)slot * I_DIM + col8 * 8;
        aDst[i] = row * 40 + col8 * 8;
    }
    // B staging: 128 rows x 32 floats = 1024 f32x4 chunks -> 4 chunks/thread
    const float* bSrc[4]; int bDst[4];
#pragma unroll
    for (int i = 0; i < 4; ++i) {
        int c = tid + i * 256;
        int row = c >> 3, col4 = c & 7;
        bSrc[i] = wd + ((size_t)e * H_DIM + nt * 128 + row) * I_DIM + col4 * 4;
        bDst[i] = row * 40 + col4 * 4;
    }

    const f32x4 zero = {0.f, 0.f, 0.f, 0.f};
    f32x4 acc[4][8];
#pragma unroll
    for (int mi = 0; mi < 4; ++mi)
#pragma unroll
        for (int ni = 0; ni < 8; ++ni) acc[mi][ni] = zero;

    int m16 = lane & 15, quad = lane >> 4;

    f16x8 aReg[4]; f32x4 bReg[4];
#pragma unroll
    for (int i = 0; i < 4; ++i) { aReg[i] = *(const f16x8*)(aSrc[i]); bReg[i] = *(const f32x4*)(bSrc[i]); }

    for (int k0 = 0; k0 < I_DIM; k0 += 32) {
#pragma unroll
        for (int i = 0; i < 4; ++i)
            *(f16x8*)&As[aDst[i]] = aReg[i];
#pragma unroll
        for (int i = 0; i < 4; ++i) {
            f16x4 h;
#pragma unroll
            for (int q = 0; q < 4; ++q) h[q] = (_Float16)bReg[i][q];
            *(f16x4*)&Bs[bDst[i]] = h;
        }
        __syncthreads();
        if (k0 + 32 < I_DIM) {
            int kn = k0 + 32;
#pragma unroll
            for (int i = 0; i < 4; ++i) { aReg[i] = *(const f16x8*)(aSrc[i] + kn); bReg[i] = *(const f32x4*)(bSrc[i] + kn); }
        }
        f16x8 a[4], bb[8];
#pragma unroll
        for (int mi = 0; mi < 4; ++mi)
            a[mi] = *(const f16x8*)&As[(wave * 64 + mi * 16 + m16) * 40 + quad * 8];
#pragma unroll
        for (int ni = 0; ni < 8; ++ni)
            bb[ni] = *(const f16x8*)&Bs[(ni * 16 + m16) * 40 + quad * 8];
#pragma unroll
        for (int mi = 0; mi < 4; ++mi)
#pragma unroll
            for (int ni = 0; ni < 8; ++ni)
                acc[mi][ni] = __builtin_amdgcn_mfma_f32_16x16x32_f16(a[mi], bb[ni], acc[mi][ni], 0, 0, 0);
        __syncthreads();
    }

#pragma unroll
    for (int mi = 0; mi < 4; ++mi) {
#pragma unroll
        for (int reg = 0; reg < 4; ++reg) {
            int rloc = wave * 64 + mi * 16 + quad * 4 + reg;
            int g = mt * 256 + rloc;
            if (g >= cnt) continue;
            int t = pair_token[base + g];
#pragma unroll
            for (int ni = 0; ni < 8; ++ni) {
                int col = nt * 128 + ni * 16 + m16;
                atomicAdd(&out[(size_t)t * H_DIM + col], acc[mi][ni][reg]);
            }
        }
    }
}

extern "C" void kernel_launch(void* const* d_in, const int* in_sizes, int n_in,
                              void* d_out, int out_size, void* d_ws, size_t ws_size,
                              hipStream_t stream) {
    const float* x  = (const float*)d_in[0];
    const float* gw = (const float*)d_in[1];
    const float* wg = (const float*)d_in[2];
    const float* wu = (const float*)d_in[3];
    const float* wd = (const float*)d_in[4];
    float* out = (float*)d_out;

    char* ws = (char*)d_ws;
    int*      sel_e      = (int*)(ws + 0);          // 64 KB
    float*    sel_w      = (float*)(ws + 65536);    // 64 KB
    int*      counts     = (int*)(ws + 131072);     // 128 B
    int*      cursor     = (int*)(ws + 131200);     // 128 B
    int*      offs       = (int*)(ws + 131328);     // 33*4 B
    int*      pair_token = (int*)(ws + 131584);     // 64 KB
    float*    pair_w     = (float*)(ws + 197120);   // 64 KB
    _Float16* xh         = (_Float16*)(ws + 262656);   // 8 MB
    _Float16* h_buf      = (_Float16*)(ws + 8651264);  // 24 MB

    hipMemsetAsync(ws + 131072, 0, 256, stream);                       // counts + cursor
    hipMemsetAsync(d_out, 0, (size_t)T_TOK * H_DIM * sizeof(float), stream);

    cvt_x_kernel<<<(T_TOK * H_DIM / 4) / 256, 256, 0, stream>>>(x, xh);
    router_kernel<<<T_TOK, 256, 0, stream>>>(x, gw, sel_e, sel_w, counts);
    scan_kernel<<<1, 64, 0, stream>>>(counts, offs);
    scatter_kernel<<<T_TOK / 256, 256, 0, stream>>>(sel_e, sel_w, offs, cursor, pair_token, pair_w);
    mlp1_kernel<<<dim3(M1_MT, M1_NT, E_NUM), 256, 0, stream>>>(xh, wg, wu, offs, pair_token, pair_w, h_buf);
    mlp2_kernel<<<dim3(M2_MT, M2_NT, E_NUM), 256, 0, stream>>>(h_buf, wd, offs, pair_token, out);
}

// Round 4
// 996.206 us; speedup vs baseline: 1.4590x; 1.4590x over previous
//
#include <hip/hip_runtime.h>

#define T_TOK 2048
#define H_DIM 2048
#define E_NUM 32
#define I_DIM 768
#define TOPK 8

typedef __attribute__((ext_vector_type(8))) _Float16 f16x8;
typedef __attribute__((ext_vector_type(4))) _Float16 f16x4;
typedef __attribute__((ext_vector_type(4))) float f32x4;

// ---------------- x fp32 -> fp16 ----------------
__global__ __launch_bounds__(256) void cvt_x_kernel(const float* __restrict__ x,
                                                    _Float16* __restrict__ xh) {
    int i = blockIdx.x * 256 + threadIdx.x;  // one f32x4 per thread
    f32x4 f = ((const f32x4*)x)[i];
    f16x4 h;
    h[0] = (_Float16)f[0]; h[1] = (_Float16)f[1];
    h[2] = (_Float16)f[2]; h[3] = (_Float16)f[3];
    ((f16x4*)xh)[i] = h;
}

// ---------------- router: logits (fp32) + top-8 + softmax ----------------
__global__ __launch_bounds__(256) void router_kernel(const float* __restrict__ x,
                                                     const float* __restrict__ gw,
                                                     int* __restrict__ sel_e,
                                                     float* __restrict__ sel_w,
                                                     int* __restrict__ counts) {
    int t = blockIdx.x;
    int tid = threadIdx.x, lane = tid & 63, wave = tid >> 6;
    __shared__ float logits[E_NUM];
    const float* xr = x + (size_t)t * H_DIM;
    float xv[32];
#pragma unroll
    for (int c = 0; c < 32; ++c) xv[c] = xr[lane + c * 64];
    for (int j = 0; j < 8; ++j) {
        int e = wave * 8 + j;
        const float* wr = gw + (size_t)e * H_DIM;
        float acc = 0.f;
#pragma unroll
        for (int c = 0; c < 32; ++c) acc += xv[c] * wr[lane + c * 64];
#pragma unroll
        for (int s = 32; s > 0; s >>= 1) acc += __shfl_xor(acc, s, 64);
        if (lane == 0) logits[e] = acc;
    }
    __syncthreads();
    if (tid == 0) {
        float lg[E_NUM];
        for (int e2 = 0; e2 < E_NUM; ++e2) lg[e2] = logits[e2];
        unsigned taken = 0;
        float sv[TOPK]; int se[TOPK];
        for (int k = 0; k < TOPK; ++k) {          // top-k, ties -> lowest index (matches lax.top_k)
            float best = -3.4e38f; int bi = 0;
            for (int e2 = 0; e2 < E_NUM; ++e2)
                if (!((taken >> e2) & 1u) && lg[e2] > best) { best = lg[e2]; bi = e2; }
            taken |= 1u << bi; sv[k] = best; se[k] = bi;
        }
        float m = sv[0], s = 0.f;
        for (int k = 0; k < TOPK; ++k) { sv[k] = expf(sv[k] - m); s += sv[k]; }
        float inv = 1.f / s;
        for (int k = 0; k < TOPK; ++k) {
            sel_e[t * TOPK + k] = se[k];
            sel_w[t * TOPK + k] = sv[k] * inv;
            atomicAdd(&counts[se[k]], 1);
        }
    }
}

// ---------------- exclusive scan over 32 expert counts ----------------
__global__ void scan_kernel(const int* __restrict__ counts, int* __restrict__ offs) {
    if (threadIdx.x == 0) {
        int s = 0;
        for (int e = 0; e < E_NUM; ++e) { offs[e] = s; s += counts[e]; }
        offs[E_NUM] = s;
    }
}

// ---------------- scatter (token,weight) pairs into per-expert lists ----------------
__global__ __launch_bounds__(256) void scatter_kernel(const int* __restrict__ sel_e,
                                                      const float* __restrict__ sel_w,
                                                      const int* __restrict__ offs,
                                                      int* __restrict__ cursor,
                                                      int* __restrict__ pair_token,
                                                      float* __restrict__ pair_w) {
    int t = blockIdx.x * 256 + threadIdx.x;
    if (t >= T_TOK) return;
    for (int k = 0; k < TOPK; ++k) {
        int e = sel_e[t * TOPK + k];
        int pos = atomicAdd(&cursor[e], 1);
        int slot = offs[e] + pos;
        pair_token[slot] = t;
        pair_w[slot] = sel_w[t * TOPK + k];
    }
}

// ---------------- mlp1: h = silu(x@Wg^T) * (x@Wu^T) * pair_w, fp16 MFMA ----------------
// BM=256 tokens, BN=64 I-cols, fused g+u (acc 128 f32/thread -> 2 blocks/CU cap).
// XCD mapping (HW: XCD = blockIdx % 8, confirmed by R3's mt%8 pathology):
//   xcd=b&7; j=b>>3; mt=j&7; slab=(j>>3)*8+xcd; e=slab/12; nt=slab%12
// -> every XCD gets an identical (mt,nt,e) work distribution (balanced), and the
// mt-twins of each (e,nt) weight slab (1 MB, fits 4 MB L2) run consecutively on the
// SAME XCD -> slab fetched from HBM ~once.
#define M1_MT 8
#define M1_NT 12
__global__ __launch_bounds__(256, 2) void mlp1_kernel(const _Float16* __restrict__ xh,
                                                      const float* __restrict__ wg,
                                                      const float* __restrict__ wu,
                                                      const int* __restrict__ offs,
                                                      const int* __restrict__ pair_token,
                                                      const float* __restrict__ pair_w,
                                                      _Float16* __restrict__ h_buf) {
    int b = blockIdx.x;
    int xcd = b & 7;
    int j = b >> 3;                 // 0..383
    int mt = j & 7;
    int slab = (j >> 3) * 8 + xcd;  // 0..383, bijective
    int e = slab / 12;
    int nt = slab % 12;
    int base = offs[e], cnt = offs[e + 1] - base;
    if (mt * 256 >= cnt) return;
    int tid = threadIdx.x, lane = tid & 63, wave = tid >> 6;

    __shared__ _Float16 As[256 * 40];   // pad stride 40 halves
    __shared__ _Float16 Bg[64 * 40];
    __shared__ _Float16 Bu[64 * 40];

    // A staging: 256 rows x 32 halves = 1024 chunks of 8 halves; 4 chunks/thread
    const _Float16* aSrc[4]; int aDst[4];
#pragma unroll
    for (int i = 0; i < 4; ++i) {
        int c = tid + i * 256;
        int row = c >> 2, col8 = c & 3;
        int g = mt * 256 + row;
        int tok = (g < cnt) ? pair_token[base + g] : pair_token[base];
        aSrc[i] = xh + (size_t)tok * H_DIM + col8 * 8;
        aDst[i] = row * 40 + col8 * 8;
    }
    // B staging: 64 rows x 32 floats per matrix = 512 f32x4 chunks; 2 chunks/thread
    const float* gSrc[2]; const float* uSrc[2]; int bDst[2];
#pragma unroll
    for (int i = 0; i < 2; ++i) {
        int c = tid + i * 256;
        int row = c >> 3, col4 = c & 7;
        size_t wOff = ((size_t)e * I_DIM + nt * 64 + row) * H_DIM + col4 * 4;
        gSrc[i] = wg + wOff; uSrc[i] = wu + wOff;
        bDst[i] = row * 40 + col4 * 4;
    }

    const f32x4 zero = {0.f, 0.f, 0.f, 0.f};
    f32x4 accg[4][4], accu[4][4];
#pragma unroll
    for (int mi = 0; mi < 4; ++mi)
#pragma unroll
        for (int ni = 0; ni < 4; ++ni) { accg[mi][ni] = zero; accu[mi][ni] = zero; }

    int m16 = lane & 15, quad = lane >> 4;

    // register prefetch (T14): regs hold slab k0; prefetch k0+32 overlaps MFMA
    f16x8 aReg[4]; f32x4 gReg[2], uReg[2];
#pragma unroll
    for (int i = 0; i < 4; ++i) aReg[i] = *(const f16x8*)(aSrc[i]);
#pragma unroll
    for (int i = 0; i < 2; ++i) { gReg[i] = *(const f32x4*)(gSrc[i]); uReg[i] = *(const f32x4*)(uSrc[i]); }

    for (int k0 = 0; k0 < H_DIM; k0 += 32) {
#pragma unroll
        for (int i = 0; i < 4; ++i)
            *(f16x8*)&As[aDst[i]] = aReg[i];
#pragma unroll
        for (int i = 0; i < 2; ++i) {
            f16x4 hg, hu;
#pragma unroll
            for (int q = 0; q < 4; ++q) { hg[q] = (_Float16)gReg[i][q]; hu[q] = (_Float16)uReg[i][q]; }
            *(f16x4*)&Bg[bDst[i]] = hg;
            *(f16x4*)&Bu[bDst[i]] = hu;
        }
        __syncthreads();
        if (k0 + 32 < H_DIM) {
            int kn = k0 + 32;
#pragma unroll
            for (int i = 0; i < 4; ++i) aReg[i] = *(const f16x8*)(aSrc[i] + kn);
#pragma unroll
            for (int i = 0; i < 2; ++i) { gReg[i] = *(const f32x4*)(gSrc[i] + kn); uReg[i] = *(const f32x4*)(uSrc[i] + kn); }
        }
        f16x8 a[4], bg[4], bu[4];
#pragma unroll
        for (int mi = 0; mi < 4; ++mi)
            a[mi] = *(const f16x8*)&As[(wave * 64 + mi * 16 + m16) * 40 + quad * 8];
#pragma unroll
        for (int ni = 0; ni < 4; ++ni) {
            int r = (ni * 16 + m16) * 40 + quad * 8;
            bg[ni] = *(const f16x8*)&Bg[r];
            bu[ni] = *(const f16x8*)&Bu[r];
        }
#pragma unroll
        for (int mi = 0; mi < 4; ++mi)
#pragma unroll
            for (int ni = 0; ni < 4; ++ni) {
                accg[mi][ni] = __builtin_amdgcn_mfma_f32_16x16x32_f16(a[mi], bg[ni], accg[mi][ni], 0, 0, 0);
                accu[mi][ni] = __builtin_amdgcn_mfma_f32_16x16x32_f16(a[mi], bu[ni], accu[mi][ni], 0, 0, 0);
            }
        __syncthreads();
    }

    // epilogue: silu(g)*u*pair_w -> h_buf (fp16). C/D: col=lane&15, row=quad*4+reg
#pragma unroll
    for (int mi = 0; mi < 4; ++mi) {
#pragma unroll
        for (int reg = 0; reg < 4; ++reg) {
            int rloc = wave * 64 + mi * 16 + quad * 4 + reg;
            int g = mt * 256 + rloc;
            if (g >= cnt) continue;
            int slot = base + g;
            float pw = pair_w[slot];
#pragma unroll
            for (int ni = 0; ni < 4; ++ni) {
                int col = nt * 64 + ni * 16 + m16;
                float gv = accg[mi][ni][reg];
                float uv = accu[mi][ni][reg];
                float hv = (gv / (1.f + expf(-gv))) * uv * pw;
                h_buf[(size_t)slot * I_DIM + col] = (_Float16)hv;
            }
        }
    }
}

// ---------------- mlp2: out[t] += h_slot @ Wd^T (scatter-add) ----------------
// BM=256 slots, BN=128 H-cols. Grid dim3(nt=16, mt=8, e=32): since 16%8==0,
// XCD = nt%8 -> every XCD sees all (mt,e) (balanced) AND mt-twins of each wd
// slab share an XCD L2.
#define M2_MT 8
#define M2_NT 16
__global__ __launch_bounds__(256, 2) void mlp2_kernel(const _Float16* __restrict__ h_buf,
                                                      const float* __restrict__ wd,
                                                      const int* __restrict__ offs,
                                                      const int* __restrict__ pair_token,
                                                      float* __restrict__ out) {
    int nt = blockIdx.x, mt = blockIdx.y, e = blockIdx.z;
    int base = offs[e], cnt = offs[e + 1] - base;
    if (mt * 256 >= cnt) return;
    int tid = threadIdx.x, lane = tid & 63, wave = tid >> 6;

    __shared__ _Float16 As[256 * 40];
    __shared__ _Float16 Bs[128 * 40];

    // A staging: 256 rows x 32 halves -> 4 chunks/thread (slots are contiguous, no gather)
    const _Float16* aSrc[4]; int aDst[4];
#pragma unroll
    for (int i = 0; i < 4; ++i) {
        int c = tid + i * 256;
        int row = c >> 2, col8 = c & 3;
        int g = mt * 256 + row;
        int slot = (g < cnt) ? (base + g) : base;  // clamp: avoid OOB reads past h_buf
        aSrc[i] = h_buf + (size_t)slot * I_DIM + col8 * 8;
        aDst[i] = row * 40 + col8 * 8;
    }
    // B staging: 128 rows x 32 floats = 1024 f32x4 chunks -> 4 chunks/thread
    const float* bSrc[4]; int bDst[4];
#pragma unroll
    for (int i = 0; i < 4; ++i) {
        int c = tid + i * 256;
        int row = c >> 3, col4 = c & 7;
        bSrc[i] = wd + ((size_t)e * H_DIM + nt * 128 + row) * I_DIM + col4 * 4;
        bDst[i] = row * 40 + col4 * 4;
    }

    const f32x4 zero = {0.f, 0.f, 0.f, 0.f};
    f32x4 acc[4][8];
#pragma unroll
    for (int mi = 0; mi < 4; ++mi)
#pragma unroll
        for (int ni = 0; ni < 8; ++ni) acc[mi][ni] = zero;

    int m16 = lane & 15, quad = lane >> 4;

    f16x8 aReg[4]; f32x4 bReg[4];
#pragma unroll
    for (int i = 0; i < 4; ++i) { aReg[i] = *(const f16x8*)(aSrc[i]); bReg[i] = *(const f32x4*)(bSrc[i]); }

    for (int k0 = 0; k0 < I_DIM; k0 += 32) {
#pragma unroll
        for (int i = 0; i < 4; ++i)
            *(f16x8*)&As[aDst[i]] = aReg[i];
#pragma unroll
        for (int i = 0; i < 4; ++i) {
            f16x4 h;
#pragma unroll
            for (int q = 0; q < 4; ++q) h[q] = (_Float16)bReg[i][q];
            *(f16x4*)&Bs[bDst[i]] = h;
        }
        __syncthreads();
        if (k0 + 32 < I_DIM) {
            int kn = k0 + 32;
#pragma unroll
            for (int i = 0; i < 4; ++i) { aReg[i] = *(const f16x8*)(aSrc[i] + kn); bReg[i] = *(const f32x4*)(bSrc[i] + kn); }
        }
        f16x8 a[4], bb[8];
#pragma unroll
        for (int mi = 0; mi < 4; ++mi)
            a[mi] = *(const f16x8*)&As[(wave * 64 + mi * 16 + m16) * 40 + quad * 8];
#pragma unroll
        for (int ni = 0; ni < 8; ++ni)
            bb[ni] = *(const f16x8*)&Bs[(ni * 16 + m16) * 40 + quad * 8];
#pragma unroll
        for (int mi = 0; mi < 4; ++mi)
#pragma unroll
            for (int ni = 0; ni < 8; ++ni)
                acc[mi][ni] = __builtin_amdgcn_mfma_f32_16x16x32_f16(a[mi], bb[ni], acc[mi][ni], 0, 0, 0);
        __syncthreads();
    }

#pragma unroll
    for (int mi = 0; mi < 4; ++mi) {
#pragma unroll
        for (int reg = 0; reg < 4; ++reg) {
            int rloc = wave * 64 + mi * 16 + quad * 4 + reg;
            int g = mt * 256 + rloc;
            if (g >= cnt) continue;
            int t = pair_token[base + g];
#pragma unroll
            for (int ni = 0; ni < 8; ++ni) {
                int col = nt * 128 + ni * 16 + m16;
                atomicAdd(&out[(size_t)t * H_DIM + col], acc[mi][ni][reg]);
            }
        }
    }
}

extern "C" void kernel_launch(void* const* d_in, const int* in_sizes, int n_in,
                              void* d_out, int out_size, void* d_ws, size_t ws_size,
                              hipStream_t stream) {
    const float* x  = (const float*)d_in[0];
    const float* gw = (const float*)d_in[1];
    const float* wg = (const float*)d_in[2];
    const float* wu = (const float*)d_in[3];
    const float* wd = (const float*)d_in[4];
    float* out = (float*)d_out;

    char* ws = (char*)d_ws;
    int*      sel_e      = (int*)(ws + 0);          // 64 KB
    float*    sel_w      = (float*)(ws + 65536);    // 64 KB
    int*      counts     = (int*)(ws + 131072);     // 128 B
    int*      cursor     = (int*)(ws + 131200);     // 128 B
    int*      offs       = (int*)(ws + 131328);     // 33*4 B
    int*      pair_token = (int*)(ws + 131584);     // 64 KB
    float*    pair_w     = (float*)(ws + 197120);   // 64 KB
    _Float16* xh         = (_Float16*)(ws + 262656);   // 8 MB
    _Float16* h_buf      = (_Float16*)(ws + 8651264);  // 24 MB

    hipMemsetAsync(ws + 131072, 0, 256, stream);                       // counts + cursor
    hipMemsetAsync(d_out, 0, (size_t)T_TOK * H_DIM * sizeof(float), stream);

    cvt_x_kernel<<<(T_TOK * H_DIM / 4) / 256, 256, 0, stream>>>(x, xh);
    router_kernel<<<T_TOK, 256, 0, stream>>>(x, gw, sel_e, sel_w, counts);
    scan_kernel<<<1, 64, 0, stream>>>(counts, offs);
    scatter_kernel<<<T_TOK / 256, 256, 0, stream>>>(sel_e, sel_w, offs, cursor, pair_token, pair_w);
    mlp1_kernel<<<M1_MT * M1_NT * E_NUM, 256, 0, stream>>>(xh, wg, wu, offs, pair_token, pair_w, h_buf);
    mlp2_kernel<<<dim3(M2_NT, M2_MT, E_NUM), 256, 0, stream>>>(h_buf, wd, offs, pair_token, out);
}

// Round 5
// 953.254 us; speedup vs baseline: 1.5247x; 1.0451x over previous
//
#include <hip/hip_runtime.h>

#define T_TOK 2048
#define H_DIM 2048
#define E_NUM 32
#define I_DIM 768
#define TOPK 8

typedef __attribute__((ext_vector_type(8))) _Float16 f16x8;
typedef __attribute__((ext_vector_type(4))) _Float16 f16x4;
typedef __attribute__((ext_vector_type(4))) float f32x4;

// ---------------- x fp32 -> fp16 ----------------
__global__ __launch_bounds__(256) void cvt_x_kernel(const float* __restrict__ x,
                                                    _Float16* __restrict__ xh) {
    int i = blockIdx.x * 256 + threadIdx.x;  // one f32x4 per thread
    f32x4 f = ((const f32x4*)x)[i];
    f16x4 h;
    h[0] = (_Float16)f[0]; h[1] = (_Float16)f[1];
    h[2] = (_Float16)f[2]; h[3] = (_Float16)f[3];
    ((f16x4*)xh)[i] = h;
}

// ---------------- router: logits (fp32) + top-8 + softmax ----------------
__global__ __launch_bounds__(256) void router_kernel(const float* __restrict__ x,
                                                     const float* __restrict__ gw,
                                                     int* __restrict__ sel_e,
                                                     float* __restrict__ sel_w,
                                                     int* __restrict__ counts) {
    int t = blockIdx.x;
    int tid = threadIdx.x, lane = tid & 63, wave = tid >> 6;
    __shared__ float logits[E_NUM];
    const float* xr = x + (size_t)t * H_DIM;
    float xv[32];
#pragma unroll
    for (int c = 0; c < 32; ++c) xv[c] = xr[lane + c * 64];
    for (int j = 0; j < 8; ++j) {
        int e = wave * 8 + j;
        const float* wr = gw + (size_t)e * H_DIM;
        float acc = 0.f;
#pragma unroll
        for (int c = 0; c < 32; ++c) acc += xv[c] * wr[lane + c * 64];
#pragma unroll
        for (int s = 32; s > 0; s >>= 1) acc += __shfl_xor(acc, s, 64);
        if (lane == 0) logits[e] = acc;
    }
    __syncthreads();
    if (tid == 0) {
        float lg[E_NUM];
        for (int e2 = 0; e2 < E_NUM; ++e2) lg[e2] = logits[e2];
        unsigned taken = 0;
        float sv[TOPK]; int se[TOPK];
        for (int k = 0; k < TOPK; ++k) {          // top-k, ties -> lowest index (matches lax.top_k)
            float best = -3.4e38f; int bi = 0;
            for (int e2 = 0; e2 < E_NUM; ++e2)
                if (!((taken >> e2) & 1u) && lg[e2] > best) { best = lg[e2]; bi = e2; }
            taken |= 1u << bi; sv[k] = best; se[k] = bi;
        }
        float m = sv[0], s = 0.f;
        for (int k = 0; k < TOPK; ++k) { sv[k] = expf(sv[k] - m); s += sv[k]; }
        float inv = 1.f / s;
        for (int k = 0; k < TOPK; ++k) {
            sel_e[t * TOPK + k] = se[k];
            sel_w[t * TOPK + k] = sv[k] * inv;
            atomicAdd(&counts[se[k]], 1);
        }
    }
}

// ---------------- exclusive scan over 32 expert counts ----------------
__global__ void scan_kernel(const int* __restrict__ counts, int* __restrict__ offs) {
    if (threadIdx.x == 0) {
        int s = 0;
        for (int e = 0; e < E_NUM; ++e) { offs[e] = s; s += counts[e]; }
        offs[E_NUM] = s;
    }
}

// ---------------- scatter (token,weight) pairs into per-expert lists ----------------
__global__ __launch_bounds__(256) void scatter_kernel(const int* __restrict__ sel_e,
                                                      const float* __restrict__ sel_w,
                                                      const int* __restrict__ offs,
                                                      int* __restrict__ cursor,
                                                      int* __restrict__ pair_token,
                                                      float* __restrict__ pair_w) {
    int t = blockIdx.x * 256 + threadIdx.x;
    if (t >= T_TOK) return;
    for (int k = 0; k < TOPK; ++k) {
        int e = sel_e[t * TOPK + k];
        int pos = atomicAdd(&cursor[e], 1);
        int slot = offs[e] + pos;
        pair_token[slot] = t;
        pair_w[slot] = sel_w[t * TOPK + k];
    }
}

// ---------------- mlp1: h = silu(x@Wg^T) * (x@Wu^T) * pair_w, fp16 MFMA ----------------
// BM=128 tokens, BN=64 I-cols, fused g+u. acc = 64 f32/thread -> target 3 blocks/CU
// (__launch_bounds__(256,3): 12 waves/CU for latency hiding; R4 showed 2 blocks/CU +
// serial K-step = 16% MfmaUtil with everything idle).
// Double-buffered LDS, ONE barrier per K-step: write buf[p^1] (regs prefetched last
// step, full-step latency cover) -> issue next loads -> ds_read buf[p] + MFMA -> barrier.
// XCD map (HW: XCD = blockIdx%8, confirmed R3): xcd=b&7; j=b>>3; mt=j&15; slab=(j>>4)*8+xcd;
// e=slab/12; nt=slab%12 -> balanced per XCD, mt-twins of each 1MB weight slab share an L2.
#define M1_MT 16
#define M1_NT 12
__global__ __launch_bounds__(256, 3) void mlp1_kernel(const _Float16* __restrict__ xh,
                                                      const float* __restrict__ wg,
                                                      const float* __restrict__ wu,
                                                      const int* __restrict__ offs,
                                                      const int* __restrict__ pair_token,
                                                      const float* __restrict__ pair_w,
                                                      _Float16* __restrict__ h_buf) {
    int b = blockIdx.x;
    int xcd = b & 7;
    int j = b >> 3;                  // 0..767
    int mt = j & 15;
    int slab = (j >> 4) * 8 + xcd;   // 0..383, bijective
    int e = slab / 12;
    int nt = slab % 12;
    int base = offs[e], cnt = offs[e + 1] - base;
    if (mt * 128 >= cnt) return;
    int tid = threadIdx.x, lane = tid & 63, wave = tid >> 6;

    __shared__ _Float16 As[2][128 * 40];   // pad stride 40 halves
    __shared__ _Float16 Bg[2][64 * 40];
    __shared__ _Float16 Bu[2][64 * 40];

    // A staging: 128 rows x 32 halves = 512 chunks of 8 halves; 2 chunks/thread
    const _Float16* aSrc[2]; int aDst[2];
#pragma unroll
    for (int i = 0; i < 2; ++i) {
        int c = tid + i * 256;
        int row = c >> 2, col8 = c & 3;
        int g = mt * 128 + row;
        int tok = (g < cnt) ? pair_token[base + g] : pair_token[base];
        aSrc[i] = xh + (size_t)tok * H_DIM + col8 * 8;
        aDst[i] = row * 40 + col8 * 8;
    }
    // B staging: 64 rows x 32 floats per matrix = 512 f32x4 chunks; 2 chunks/thread each
    const float* gSrc[2]; const float* uSrc[2]; int bDst[2];
#pragma unroll
    for (int i = 0; i < 2; ++i) {
        int c = tid + i * 256;
        int row = c >> 3, col4 = c & 7;
        size_t wOff = ((size_t)e * I_DIM + nt * 64 + row) * H_DIM + col4 * 4;
        gSrc[i] = wg + wOff; uSrc[i] = wu + wOff;
        bDst[i] = row * 40 + col4 * 4;
    }

    const f32x4 zero = {0.f, 0.f, 0.f, 0.f};
    f32x4 accg[4][2], accu[4][2];
#pragma unroll
    for (int mi = 0; mi < 4; ++mi)
#pragma unroll
        for (int ni = 0; ni < 2; ++ni) { accg[mi][ni] = zero; accu[mi][ni] = zero; }

    int m16 = lane & 15, quad = lane >> 4, wm = wave >> 1, wn = wave & 1;

    // prefetch registers (one K-slab in flight)
    f16x8 aReg[2]; f32x4 gReg[2], uReg[2];
#pragma unroll
    for (int i = 0; i < 2; ++i) aReg[i] = *(const f16x8*)(aSrc[i]);
#pragma unroll
    for (int i = 0; i < 2; ++i) { gReg[i] = *(const f32x4*)(gSrc[i]); uReg[i] = *(const f32x4*)(uSrc[i]); }

    // prologue: fill buf 0 with k=0, then issue loads for k=32
#pragma unroll
    for (int i = 0; i < 2; ++i) *(f16x8*)&As[0][aDst[i]] = aReg[i];
#pragma unroll
    for (int i = 0; i < 2; ++i) {
        f16x4 hg, hu;
#pragma unroll
        for (int q = 0; q < 4; ++q) { hg[q] = (_Float16)gReg[i][q]; hu[q] = (_Float16)uReg[i][q]; }
        *(f16x4*)&Bg[0][bDst[i]] = hg;
        *(f16x4*)&Bu[0][bDst[i]] = hu;
    }
    __syncthreads();
#pragma unroll
    for (int i = 0; i < 2; ++i) aReg[i] = *(const f16x8*)(aSrc[i] + 32);
#pragma unroll
    for (int i = 0; i < 2; ++i) { gReg[i] = *(const f32x4*)(gSrc[i] + 32); uReg[i] = *(const f32x4*)(uSrc[i] + 32); }

    int p = 0;
    for (int k0 = 0; k0 < H_DIM; k0 += 32) {
        int nxt = k0 + 32;
        if (nxt < H_DIM) {
            // write NEXT slab into the other buffer (other waves finished reading it
            // before the previous barrier); regs had a full step of latency cover
#pragma unroll
            for (int i = 0; i < 2; ++i) *(f16x8*)&As[p ^ 1][aDst[i]] = aReg[i];
#pragma unroll
            for (int i = 0; i < 2; ++i) {
                f16x4 hg, hu;
#pragma unroll
                for (int q = 0; q < 4; ++q) { hg[q] = (_Float16)gReg[i][q]; hu[q] = (_Float16)uReg[i][q]; }
                *(f16x4*)&Bg[p ^ 1][bDst[i]] = hg;
                *(f16x4*)&Bu[p ^ 1][bDst[i]] = hu;
            }
            if (nxt + 32 < H_DIM) {  // issue loads for the slab after next
                int kn = nxt + 32;
#pragma unroll
                for (int i = 0; i < 2; ++i) aReg[i] = *(const f16x8*)(aSrc[i] + kn);
#pragma unroll
                for (int i = 0; i < 2; ++i) { gReg[i] = *(const f32x4*)(gSrc[i] + kn); uReg[i] = *(const f32x4*)(uSrc[i] + kn); }
            }
        }
        f16x8 a[4], bg[2], bu[2];
#pragma unroll
        for (int mi = 0; mi < 4; ++mi)
            a[mi] = *(const f16x8*)&As[p][(wm * 64 + mi * 16 + m16) * 40 + quad * 8];
#pragma unroll
        for (int ni = 0; ni < 2; ++ni) {
            int r = (wn * 32 + ni * 16 + m16) * 40 + quad * 8;
            bg[ni] = *(const f16x8*)&Bg[p][r];
            bu[ni] = *(const f16x8*)&Bu[p][r];
        }
#pragma unroll
        for (int mi = 0; mi < 4; ++mi)
#pragma unroll
            for (int ni = 0; ni < 2; ++ni) {
                accg[mi][ni] = __builtin_amdgcn_mfma_f32_16x16x32_f16(a[mi], bg[ni], accg[mi][ni], 0, 0, 0);
                accu[mi][ni] = __builtin_amdgcn_mfma_f32_16x16x32_f16(a[mi], bu[ni], accu[mi][ni], 0, 0, 0);
            }
        __syncthreads();   // writes to buf[p^1] visible; reads of buf[p] complete
        p ^= 1;
    }

    // epilogue: silu(g)*u*pair_w -> h_buf (fp16). C/D: col=lane&15, row=quad*4+reg
#pragma unroll
    for (int mi = 0; mi < 4; ++mi) {
#pragma unroll
        for (int reg = 0; reg < 4; ++reg) {
            int rloc = wm * 64 + mi * 16 + quad * 4 + reg;
            int g = mt * 128 + rloc;
            if (g >= cnt) continue;
            int slot = base + g;
            float pw = pair_w[slot];
#pragma unroll
            for (int ni = 0; ni < 2; ++ni) {
                int col = nt * 64 + wn * 32 + ni * 16 + m16;
                float gv = accg[mi][ni][reg];
                float uv = accu[mi][ni][reg];
                float hv = (gv / (1.f + expf(-gv))) * uv * pw;
                h_buf[(size_t)slot * I_DIM + col] = (_Float16)hv;
            }
        }
    }
}

// ---------------- mlp2: out[t] += h_slot @ Wd^T (scatter-add) ----------------
// BM=128 slots, BN=128 H-cols, acc 64 f32/thread, 3 blocks/CU target, same dbuf
// single-barrier pipeline. XCD map: xcd=b&7; j=b>>3; mt=j&15; slab=(j>>4)*8+xcd;
// e=slab>>4; nt=slab&15 (wd slab 384KB -> L2-resident for mt-twins).
#define M2_MT 16
#define M2_NT 16
__global__ __launch_bounds__(256, 3) void mlp2_kernel(const _Float16* __restrict__ h_buf,
                                                      const float* __restrict__ wd,
                                                      const int* __restrict__ offs,
                                                      const int* __restrict__ pair_token,
                                                      float* __restrict__ out) {
    int b = blockIdx.x;
    int xcd = b & 7;
    int j = b >> 3;                  // 0..1023
    int mt = j & 15;
    int slab = (j >> 4) * 8 + xcd;   // 0..511, bijective
    int e = slab >> 4;
    int nt = slab & 15;
    int base = offs[e], cnt = offs[e + 1] - base;
    if (mt * 128 >= cnt) return;
    int tid = threadIdx.x, lane = tid & 63, wave = tid >> 6;

    __shared__ _Float16 As[2][128 * 40];
    __shared__ _Float16 Bs[2][128 * 40];

    // A staging: 128 rows x 32 halves -> 2 chunks/thread (slots contiguous, no gather)
    const _Float16* aSrc[2]; int aDst[2];
#pragma unroll
    for (int i = 0; i < 2; ++i) {
        int c = tid + i * 256;
        int row = c >> 2, col8 = c & 3;
        int g = mt * 128 + row;
        int slot = (g < cnt) ? (base + g) : base;  // clamp: avoid OOB reads past h_buf
        aSrc[i] = h_buf + (size_t)slot * I_DIM + col8 * 8;
        aDst[i] = row * 40 + col8 * 8;
    }
    // B staging: 128 rows x 32 floats = 1024 f32x4 chunks -> 4 chunks/thread
    const float* bSrc[4]; int bDst[4];
#pragma unroll
    for (int i = 0; i < 4; ++i) {
        int c = tid + i * 256;
        int row = c >> 3, col4 = c & 7;
        bSrc[i] = wd + ((size_t)e * H_DIM + nt * 128 + row) * I_DIM + col4 * 4;
        bDst[i] = row * 40 + col4 * 4;
    }

    const f32x4 zero = {0.f, 0.f, 0.f, 0.f};
    f32x4 acc[4][4];
#pragma unroll
    for (int mi = 0; mi < 4; ++mi)
#pragma unroll
        for (int ni = 0; ni < 4; ++ni) acc[mi][ni] = zero;

    int m16 = lane & 15, quad = lane >> 4, wm = wave >> 1, wn = wave & 1;

    f16x8 aReg[2]; f32x4 bReg[4];
#pragma unroll
    for (int i = 0; i < 2; ++i) aReg[i] = *(const f16x8*)(aSrc[i]);
#pragma unroll
    for (int i = 0; i < 4; ++i) bReg[i] = *(const f32x4*)(bSrc[i]);

    // prologue: fill buf 0, issue loads for k=32
#pragma unroll
    for (int i = 0; i < 2; ++i) *(f16x8*)&As[0][aDst[i]] = aReg[i];
#pragma unroll
    for (int i = 0; i < 4; ++i) {
        f16x4 h;
#pragma unroll
        for (int q = 0; q < 4; ++q) h[q] = (_Float16)bReg[i][q];
        *(f16x4*)&Bs[0][bDst[i]] = h;
    }
    __syncthreads();
#pragma unroll
    for (int i = 0; i < 2; ++i) aReg[i] = *(const f16x8*)(aSrc[i] + 32);
#pragma unroll
    for (int i = 0; i < 4; ++i) bReg[i] = *(const f32x4*)(bSrc[i] + 32);

    int p = 0;
    for (int k0 = 0; k0 < I_DIM; k0 += 32) {
        int nxt = k0 + 32;
        if (nxt < I_DIM) {
#pragma unroll
            for (int i = 0; i < 2; ++i) *(f16x8*)&As[p ^ 1][aDst[i]] = aReg[i];
#pragma unroll
            for (int i = 0; i < 4; ++i) {
                f16x4 h;
#pragma unroll
                for (int q = 0; q < 4; ++q) h[q] = (_Float16)bReg[i][q];
                *(f16x4*)&Bs[p ^ 1][bDst[i]] = h;
            }
            if (nxt + 32 < I_DIM) {
                int kn = nxt + 32;
#pragma unroll
                for (int i = 0; i < 2; ++i) aReg[i] = *(const f16x8*)(aSrc[i] + kn);
#pragma unroll
                for (int i = 0; i < 4; ++i) bReg[i] = *(const f32x4*)(bSrc[i] + kn);
            }
        }
        f16x8 a[4], bb[4];
#pragma unroll
        for (int mi = 0; mi < 4; ++mi)
            a[mi] = *(const f16x8*)&As[p][(wm * 64 + mi * 16 + m16) * 40 + quad * 8];
#pragma unroll
        for (int ni = 0; ni < 4; ++ni)
            bb[ni] = *(const f16x8*)&Bs[p][(wn * 64 + ni * 16 + m16) * 40 + quad * 8];
#pragma unroll
        for (int mi = 0; mi < 4; ++mi)
#pragma unroll
            for (int ni = 0; ni < 4; ++ni)
                acc[mi][ni] = __builtin_amdgcn_mfma_f32_16x16x32_f16(a[mi], bb[ni], acc[mi][ni], 0, 0, 0);
        __syncthreads();
        p ^= 1;
    }

#pragma unroll
    for (int mi = 0; mi < 4; ++mi) {
#pragma unroll
        for (int reg = 0; reg < 4; ++reg) {
            int rloc = wm * 64 + mi * 16 + quad * 4 + reg;
            int g = mt * 128 + rloc;
            if (g >= cnt) continue;
            int t = pair_token[base + g];
#pragma unroll
            for (int ni = 0; ni < 4; ++ni) {
                int col = nt * 128 + wn * 64 + ni * 16 + m16;
                atomicAdd(&out[(size_t)t * H_DIM + col], acc[mi][ni][reg]);
            }
        }
    }
}

extern "C" void kernel_launch(void* const* d_in, const int* in_sizes, int n_in,
                              void* d_out, int out_size, void* d_ws, size_t ws_size,
                              hipStream_t stream) {
    const float* x  = (const float*)d_in[0];
    const float* gw = (const float*)d_in[1];
    const float* wg = (const float*)d_in[2];
    const float* wu = (const float*)d_in[3];
    const float* wd = (const float*)d_in[4];
    float* out = (float*)d_out;

    char* ws = (char*)d_ws;
    int*      sel_e      = (int*)(ws + 0);          // 64 KB
    float*    sel_w      = (float*)(ws + 65536);    // 64 KB
    int*      counts     = (int*)(ws + 131072);     // 128 B
    int*      cursor     = (int*)(ws + 131200);     // 128 B
    int*      offs       = (int*)(ws + 131328);     // 33*4 B
    int*      pair_token = (int*)(ws + 131584);     // 64 KB
    float*    pair_w     = (float*)(ws + 197120);   // 64 KB
    _Float16* xh         = (_Float16*)(ws + 262656);   // 8 MB
    _Float16* h_buf      = (_Float16*)(ws + 8651264);  // 24 MB

    hipMemsetAsync(ws + 131072, 0, 256, stream);                       // counts + cursor
    hipMemsetAsync(d_out, 0, (size_t)T_TOK * H_DIM * sizeof(float), stream);

    cvt_x_kernel<<<(T_TOK * H_DIM / 4) / 256, 256, 0, stream>>>(x, xh);
    router_kernel<<<T_TOK, 256, 0, stream>>>(x, gw, sel_e, sel_w, counts);
    scan_kernel<<<1, 64, 0, stream>>>(counts, offs);
    scatter_kernel<<<T_TOK / 256, 256, 0, stream>>>(sel_e, sel_w, offs, cursor, pair_token, pair_w);
    mlp1_kernel<<<M1_MT * M1_NT * E_NUM, 256, 0, stream>>>(xh, wg, wu, offs, pair_token, pair_w, h_buf);
    mlp2_kernel<<<M2_MT * M2_NT * E_NUM, 256, 0, stream>>>(h_buf, wd, offs, pair_token, out);
}